// Round 9
// baseline (1030.146 us; speedup 1.0000x reference)
//
#include <hip/hip_runtime.h>

// R9: scores/PV use the 4-wave 128x128 dbuf core (best measured for big
// GEMMs, R6); QKV/OP keep the 8-wave 256x128 core (best for short-K, R8).
// Fused epilogues: EPI6 P'=exp(as-4)+row-sums, EPI7 scale 1/l, EPI3 merged
// QKV routing, EPI5 split-K atomic. Launches merged 14 -> 11.

typedef short s8v __attribute__((ext_vector_type(8)));   // 8 bf16 = 4 VGPRs
typedef float f4v __attribute__((ext_vector_type(4)));
typedef unsigned short us;
typedef us us4v __attribute__((ext_vector_type(4)));

__device__ inline us f2b(float f) {  // fp32 -> bf16 RNE
  union { float f; unsigned u; } v; v.f = f;
  unsigned r = v.u + 0x7FFFu + ((v.u >> 16) & 1u);
  return (us)(r >> 16);
}

// async global->LDS, 16 B per lane; LDS dest = wave-uniform base + lane*16.
__device__ inline void gld16(const us* g, us* l) {
  __builtin_amdgcn_global_load_lds(
      (const __attribute__((address_space(1))) void*)g,
      (__attribute__((address_space(3))) void*)l, 16, 0, 0);
}

// ---------- 4-wave 128x128 core (scores / PV) ----------
// EPI 6: P' = bf16(exp(alpha*s - 4)) to Cv; row sums atomicAdd to C2[bz*2048].
// EPI 7: bf16(acc / l[row]) to Cv; l from C2[bz*2048].
template <int EPI>
__global__ __launch_bounds__(256, 4) void gemm4(
    const us* __restrict__ A, int lda, long long sA0, long long sA1,
    const us* __restrict__ Bm, int ldb, long long sB0, long long sB1,
    void* __restrict__ Cv, float* __restrict__ C2,
    int ldc, long long sC0, long long sC1,
    int K, float alpha, int L) {
  __shared__ us As[2][4096];  // 128 x 32 per buf, fragment-linear
  __shared__ us Bs[2][4096];
  const int t = threadIdx.x;
  const int wv = t >> 6, ln = t & 63;
  const int m16 = ln & 15, quad = ln >> 4;

  // XCD-aware swizzle (flat%8 -> XCD): contiguous nid range per XCD.
  const int gx = gridDim.x, gxy = gx * gridDim.y;
  const int nblk = gxy * gridDim.z;
  const int flat = blockIdx.x + gx * blockIdx.y + gxy * blockIdx.z;
  int nid = flat;
  if ((nblk & 7) == 0) nid = (flat & 7) * (nblk >> 3) + (flat >> 3);
  const int bz = nid / gxy, rem = nid % gxy;
  const int by = rem / gx, bx = rem % gx;

  const long long row0 = (long long)by * 128;
  const long long col0 = (long long)bx * 128;
  const int zo = bz >> L, zi = bz & ((1 << L) - 1);
  const us* Az = A + zo * sA0 + zi * sA1;
  const us* Bz = Bm + zo * sB0 + zi * sB1;

  int offA[2], offB[2];
#pragma unroll
  for (int j = 0; j < 2; ++j) {
    const int c = t + 256 * j;
    const int mb = c >> 6, qd = (c >> 4) & 3, mm = c & 15;
    offA[j] = (int)((row0 + mb * 16 + mm) * (long long)lda + qd * 8);
    offB[j] = (int)((col0 + mb * 16 + mm) * (long long)ldb + qd * 8);
  }

  f4v acc[4][4];
#pragma unroll
  for (int r = 0; r < 4; ++r)
#pragma unroll
    for (int c = 0; c < 4; ++c) acc[r][c] = (f4v){0.f, 0.f, 0.f, 0.f};

  const int nk = K >> 5;
  const int fo = quad * 16 + m16;

#pragma unroll
  for (int j = 0; j < 2; ++j) {
    gld16(Az + offA[j], (us*)As[0] + (256 * j + wv * 64) * 8);
    gld16(Bz + offB[j], (us*)Bs[0] + (256 * j + wv * 64) * 8);
  }

  for (int i = 0; i < nk; ++i) {
    __syncthreads();
    const int cur = i & 1;
    if (i + 1 < nk) {
      const int kof = (i + 1) << 5;
#pragma unroll
      for (int j = 0; j < 2; ++j) {
        gld16(Az + offA[j] + kof, (us*)As[cur ^ 1] + (256 * j + wv * 64) * 8);
        gld16(Bz + offB[j] + kof, (us*)Bs[cur ^ 1] + (256 * j + wv * 64) * 8);
      }
    }
    s8v af[4], bf[4];
#pragma unroll
    for (int r = 0; r < 4; ++r)
      af[r] = *(const s8v*)&As[cur][(((wv & 1) * 4 + r) * 64 + fo) * 8];
#pragma unroll
    for (int c = 0; c < 4; ++c)
      bf[c] = *(const s8v*)&Bs[cur][(((wv >> 1) * 4 + c) * 64 + fo) * 8];
#pragma unroll
    for (int r = 0; r < 4; ++r)
#pragma unroll
      for (int c = 0; c < 4; ++c)
        acc[r][c] = __builtin_amdgcn_mfma_f32_16x16x32_bf16(af[r], bf[c], acc[r][c], 0, 0, 0);
  }

  // Epilogue. C/D layout: col = lane&15, row = quad*4 + reg.
  if (EPI == 6) {
#pragma unroll
    for (int r = 0; r < 4; ++r)
#pragma unroll
      for (int c = 0; c < 4; ++c)
#pragma unroll
        for (int g = 0; g < 4; ++g)
          acc[r][c][g] = __expf(fmaf(acc[r][c][g], alpha, -4.f));
  }
#pragma unroll
  for (int r = 0; r < 4; ++r) {
    const long long gr0 = row0 + (wv & 1) * 64 + r * 16 + quad * 4;
#pragma unroll
    for (int c = 0; c < 4; ++c) {
      const long long gc = col0 + (wv >> 1) * 64 + c * 16 + m16;
      us* C = (us*)Cv + zo * sC0 + zi * sC1;
      if (EPI == 6) {
#pragma unroll
        for (int g = 0; g < 4; ++g)
          C[(gr0 + g) * (long long)ldc + gc] = f2b(acc[r][c][g]);
      } else {  // EPI 7
        const float* lrow = C2 + (long long)bz * 2048;
#pragma unroll
        for (int g = 0; g < 4; ++g) {
          const float inv = 1.f / lrow[gr0 + g];
          C[(gr0 + g) * (long long)ldc + gc] = f2b(acc[r][c][g] * inv);
        }
      }
    }
    if (EPI == 6) {  // row-sum partials over this wave's 64 cols
      float* lsum = C2 + (long long)bz * 2048;
#pragma unroll
      for (int g = 0; g < 4; ++g) {
        float s = acc[r][0][g] + acc[r][1][g] + acc[r][2][g] + acc[r][3][g];
        s += __shfl_xor(s, 1, 64);
        s += __shfl_xor(s, 2, 64);
        s += __shfl_xor(s, 4, 64);
        s += __shfl_xor(s, 8, 64);
        if (m16 == 0) atomicAdd(&lsum[gr0 + g], s);
      }
    }
  }
}

// ---------- 8-wave 256x128 core (QKV / out-proj) ----------
// EPI 3: merged QKV routing (q/k straight+bias, v transposed+bias).
// EPI 5: fp32 atomicAdd into Cv (split-K out-projection).
template <int EPI>
__global__ __launch_bounds__(512, 4) void gemm8(
    const us* __restrict__ A, int lda, long long sA0, long long sA1,
    const us* __restrict__ Bm, int ldb, long long sB0, long long sB1,
    const float* __restrict__ bias, const float* __restrict__ bias2,
    const float* __restrict__ bias3,
    void* __restrict__ Cv, void* __restrict__ C2, void* __restrict__ C3,
    int ldc, long long sC0, long long sC1,
    int K, float alpha, int L, int sbits) {
  __shared__ us As[2][8192];  // 256 x 32 per buf (1024 chunks)
  __shared__ us Bs[2][4096];  // 128 x 32 per buf (512 chunks)
  const int t = threadIdx.x;
  const int wv = t >> 6, ln = t & 63;
  const int m16 = ln & 15, quad = ln >> 4;

  const int gx = gridDim.x, gxy = gx * gridDim.y;
  const int nblk = gxy * gridDim.z;
  const int flat = blockIdx.x + gx * blockIdx.y + gxy * blockIdx.z;
  int nid = flat;
  if ((nblk & 7) == 0) nid = (flat & 7) * (nblk >> 3) + (flat >> 3);
  const int bz = nid / gxy, rem = nid % gxy;
  const int by = rem / gx, bx = rem % gx;

  const long long row0 = (long long)by * 256;
  const long long col0 = (long long)bx * 128;
  const int zo = bz >> L, zi = bz & ((1 << L) - 1);
  const us* Az = A + zo * sA0 + zi * sA1;
  const us* Bz = Bm + zo * sB0 + zi * sB1;

  int offA[2], offB;
#pragma unroll
  for (int j = 0; j < 2; ++j) {
    const int c = t + 512 * j;
    const int mb = c >> 6, qd = (c >> 4) & 3, mm = c & 15;
    offA[j] = (int)((row0 + mb * 16 + mm) * (long long)lda + qd * 8);
  }
  {
    const int mb = t >> 6, qd = (t >> 4) & 3, mm = t & 15;
    offB = (int)((col0 + mb * 16 + mm) * (long long)ldb + qd * 8);
  }

  f4v acc[4][4];
#pragma unroll
  for (int r = 0; r < 4; ++r)
#pragma unroll
    for (int c = 0; c < 4; ++c) acc[r][c] = (f4v){0.f, 0.f, 0.f, 0.f};

  const int nk = K >> 5;
  const int fo = quad * 16 + m16;
  const int arow = wv & 3, bcol = wv >> 2;

#pragma unroll
  for (int j = 0; j < 2; ++j)
    gld16(Az + offA[j], (us*)As[0] + (512 * j + wv * 64) * 8);
  gld16(Bz + offB, (us*)Bs[0] + (wv * 64) * 8);

  for (int i = 0; i < nk; ++i) {
    __syncthreads();
    const int cur = i & 1;
    if (i + 1 < nk) {
      const int kof = (i + 1) << 5;
#pragma unroll
      for (int j = 0; j < 2; ++j)
        gld16(Az + offA[j] + kof, (us*)As[cur ^ 1] + (512 * j + wv * 64) * 8);
      gld16(Bz + offB + kof, (us*)Bs[cur ^ 1] + (wv * 64) * 8);
    }
    s8v af[4], bf[4];
#pragma unroll
    for (int r = 0; r < 4; ++r)
      af[r] = *(const s8v*)&As[cur][((arow * 4 + r) * 64 + fo) * 8];
#pragma unroll
    for (int c = 0; c < 4; ++c)
      bf[c] = *(const s8v*)&Bs[cur][((bcol * 4 + c) * 64 + fo) * 8];
#pragma unroll
    for (int r = 0; r < 4; ++r)
#pragma unroll
      for (int c = 0; c < 4; ++c)
        acc[r][c] = __builtin_amdgcn_mfma_f32_16x16x32_bf16(af[r], bf[c], acc[r][c], 0, 0, 0);
  }

#pragma unroll
  for (int r = 0; r < 4; ++r) {
    const long long gr0 = row0 + arow * 64 + r * 16 + quad * 4;
#pragma unroll
    for (int c = 0; c < 4; ++c) {
      const long long gc = col0 + bcol * 64 + c * 16 + m16;
      if (EPI == 3) {
        const int which = (int)(gc >> sbits);
        const int gsec = (int)gc & ((1 << sbits) - 1);
        const int hc = gsec >> 9, e = (int)gc & 511;
        const long long slice =
            ((long long)zo * (1 << (sbits - 9)) + hc) * 1048576LL;  // S*E
        if (which == 0) {
          us* C = (us*)Cv;
          const float bb = bias[gsec];
#pragma unroll
          for (int g = 0; g < 4; ++g)
            C[slice + (gr0 + g) * 512 + e] = f2b(acc[r][c][g] + bb);
        } else if (which == 1) {
          us* C = (us*)C2;
          const float bb = bias2[gsec];
#pragma unroll
          for (int g = 0; g < 4; ++g)
            C[slice + (gr0 + g) * 512 + e] = f2b(acc[r][c][g] + bb);
        } else {
          us* C = (us*)C3;
          const float bb = bias3[gsec];
          us4v pk;
#pragma unroll
          for (int g = 0; g < 4; ++g) pk[g] = f2b(acc[r][c][g] + bb);
          *(us4v*)&C[slice + (long long)e * 2048 + gr0] = pk;
        }
      } else {  // EPI 5
        float* C = (float*)Cv + zo * sC0;
        float* p = C + gr0 * ldc + gc;
#pragma unroll
        for (int g = 0; g < 4; ++g)
          atomicAdd(&p[(long long)g * ldc], acc[r][c][g] * alpha);
      }
    }
  }
}

// prep: out[b,s,:] = bp; lb = 0; xh = bf16(x). One launch.
__global__ __launch_bounds__(256) void prep_kernel(const float* __restrict__ x,
                                                   us* __restrict__ xh,
                                                   float* __restrict__ out,
                                                   const float* __restrict__ bp,
                                                   float* __restrict__ lz) {
  const int i = blockIdx.x * 256 + threadIdx.x;
  if (i < 4194304) out[i] = bp[i & 511];
  else if (i < 4194304 + 65536) lz[i - 4194304] = 0.f;
  if (i < 1048576) {
    const float4 f = ((const float4*)x)[i];
    us4v o;
    o[0] = f2b(f.x); o[1] = f2b(f.y); o[2] = f2b(f.z); o[3] = f2b(f.w);
    ((us4v*)xh)[i] = o;
  }
}

// Transpose Wq/Wk/Wv [H][D][E] fp32 -> W3 packed bf16 (z = sec*H + head).
__global__ __launch_bounds__(256) void convT_qkv(const float* __restrict__ Wq,
                                                 const float* __restrict__ Wk,
                                                 const float* __restrict__ Wv,
                                                 us* __restrict__ W3,
                                                 int Lh, int mask,
                                                 long long sChunk) {
  __shared__ float tile[32][33];
  const int tx = threadIdx.x & 31, ty = threadIdx.x >> 5;
  const int z = blockIdx.z;
  const int sec = z >> 3, hd = z & 7;
  const float* in = (sec == 0 ? Wq : sec == 1 ? Wk : Wv) + (long long)hd * 262144;
  us* dst = W3 + (long long)(hd >> Lh) * sChunk +
            (long long)sec * ((long long)(mask + 1) * 262144) +
            (long long)(hd & mask) * 262144;
  const int r0 = blockIdx.y * 32, c0 = blockIdx.x * 32;
#pragma unroll
  for (int j = 0; j < 4; ++j)
    tile[ty + 8 * j][tx] = in[(long long)(r0 + ty + 8 * j) * 512 + c0 + tx];
  __syncthreads();
#pragma unroll
  for (int j = 0; j < 4; ++j)
    dst[(long long)(c0 + ty + 8 * j) * 512 + r0 + tx] = f2b(tile[tx][ty + 8 * j]);
}

// Wp [HE][D] fp32 -> WpT [D][HE] bf16
__global__ __launch_bounds__(256) void convT_wp(const float* __restrict__ in,
                                                us* __restrict__ out) {
  __shared__ float tile[32][33];
  const int tx = threadIdx.x & 31, ty = threadIdx.x >> 5;
  const int r0 = blockIdx.y * 32, c0 = blockIdx.x * 32;
#pragma unroll
  for (int j = 0; j < 4; ++j)
    tile[ty + 8 * j][tx] = in[(long long)(r0 + ty + 8 * j) * 512 + c0 + tx];
  __syncthreads();
#pragma unroll
  for (int j = 0; j < 4; ++j)
    out[(long long)(c0 + ty + 8 * j) * 4096 + r0 + tx] = f2b(tile[tx][ty + 8 * j]);
}

extern "C" void kernel_launch(void* const* d_in, const int* in_sizes, int n_in,
                              void* d_out, int out_size, void* d_ws, size_t ws_size,
                              hipStream_t stream) {
  constexpr int Bb = 4, S = 2048, D = 512, H = 8, E = 512, HE = 4096;
  const float* x  = (const float*)d_in[0];
  const float* Wq = (const float*)d_in[1];
  const float* bq = (const float*)d_in[2];
  const float* Wk = (const float*)d_in[3];
  const float* bk = (const float*)d_in[4];
  const float* Wv = (const float*)d_in[5];
  const float* bv = (const float*)d_in[6];
  const float* Wp = (const float*)d_in[7];
  const float* bp = (const float*)d_in[8];
  float* out = (float*)d_out;

  const long long SE = (long long)S * E, SS = (long long)S * S;
  const long long SD = (long long)S * D, ED = (long long)E * D;

  us* xh  = (us*)d_ws;            // B*S*D          4,194,304
  us* W3  = xh + 4194304;         // [chunk][3][HC*E][D]  6,291,456
  us* WpT = W3 + 6291456;         // [D][HE]        2,097,152
  us* dyn = WpT + 2097152;

  const size_t fixedB = (size_t)(4194304 + 6291456 + 2097152) * 2;
  const size_t lB = (size_t)H * Bb * S * 4;
  int HC = 8;
  while (HC > 1) {
    const size_t need = fixedB + lB +
        (size_t)HC * (3 * (size_t)Bb * SE + (size_t)Bb * SS) * 2;
    if (need <= ws_size) break;
    HC >>= 1;
  }
  const int Lh = (HC == 8) ? 3 : (HC == 4) ? 2 : (HC == 2) ? 1 : 0;
  const int BHC = Bb * HC;
  const int sbits = 9 + Lh;

  us* qh = dyn;                       // [b*HC+hc][S][E]
  us* kh = qh + (size_t)BHC * SE;
  us* vT = kh + (size_t)BHC * SE;     // [b*HC+hc][E][S]
  us* sc = vT + (size_t)BHC * SE;     // [b*HC+hc][S][S]  (P')
  float* lb = (float*)(sc + (size_t)BHC * SS);
  us* oh = qh;                        // alias: [b][S][HC][E]

  const dim3 tb(256), tg(512);
  prep_kernel<<<dim3((4194304 + 65536 + 255) / 256), tb, 0, stream>>>(
      x, xh, out, bp, lb);
  const long long sChunk = 3LL * HC * ED;
  convT_qkv<<<dim3(16, 16, 24), tb, 0, stream>>>(Wq, Wk, Wv, W3, Lh, HC - 1, sChunk);
  convT_wp<<<dim3(16, 128, 1), tb, 0, stream>>>(Wp, WpT);

  const float aS = 0.044194173824159216f;  // 1/sqrt(512)
  const dim3 gQKV(3 * HC * E / 128, 8, Bb);   // 8-wave, 256-row tiles
  const dim3 gS(16, 16, BHC);                 // 4-wave, 128x128
  const dim3 gPV(4, 16, BHC);                 // 4-wave
  const dim3 gOP(4, 8, BHC);                  // 8-wave, split-K z=(b,j)

  for (int c = 0; c < H / HC; ++c) {
    const int h0 = c * HC;
    float* lc = lb + (long long)c * BHC * S;
    gemm8<3><<<gQKV, tg, 0, stream>>>(
        xh, D, SD, 0, W3 + c * sChunk, D, 0, 0,
        bq + h0 * E, bk + h0 * E, bv + h0 * E,
        qh, kh, vT, 512, 0, SE, D, 1.f, 0, sbits);
    gemm4<6><<<gS, tb, 0, stream>>>(
        qh, E, (long long)HC * SE, SE, kh, E, (long long)HC * SE, SE,
        sc, lc, S, (long long)HC * SS, SS, E, aS, Lh);
    gemm4<7><<<gPV, tb, 0, stream>>>(
        sc, S, (long long)HC * SS, SS, vT, S, (long long)HC * SE, SE,
        oh, lc, HC * E, (long long)S * HC * E, E, S, 1.f, Lh);
    gemm8<5><<<gOP, tg, 0, stream>>>(
        oh, HC * E, (long long)S * HC * E, 512,
        WpT + (long long)h0 * E, HE, 0, 512,
        nullptr, nullptr, nullptr, out, nullptr, nullptr,
        D, SD, 0, 512, 1.f, Lh, 0);
  }
}